// Round 8
// baseline (238.119 us; speedup 1.0000x reference)
//
#include <hip/hip_runtime.h>
#include <math.h>

// SPGG Fermi update, L=4096 periodic lattice — register-streaming v3.
// v2 -> v3: revert nontemporal STORES to cached stores. rocprof showed nt
// stores caused ~2x write amplification (WRITE_SIZE 134 MB vs 64 MB output):
// nt bypasses L2 merging, so partial sectors / 16B lane-chunks never
// coalesce. Cached stores let L2 merge across strips -> exact 64 MB.
// nt LOADS kept for single-use lp/dir (full-burst pattern, keeps L2 for t).
// f32 op order identical to the verified absmax-0.0 kernels.

#define LSZ 4096
#define LMASK 4095
#define STRIPS 18        // 18 * 232 = 4176 >= 4096 (overlaps write identical values)
#define OUTW 232         // valid output cols per strip (lanes 3..60)
#define BANDH 8          // rows per wave

typedef float v4f __attribute__((ext_vector_type(4)));
typedef int   v4i __attribute__((ext_vector_type(4)));

__device__ __forceinline__ v4f a_row(v4f tm, v4f tc, v4f tp,
                                     int lm1, int lp1, float& tl, float& tr) {
    tl = __shfl(tc.w, lm1);
    tr = __shfl(tc.x, lp1);
    v4f n, a;
    // reference order: ((((center + up) + down) + left) + right)
    n.x = (((tc.x + tm.x) + tp.x) + tl)   + tc.y;
    n.y = (((tc.y + tm.y) + tp.y) + tc.x) + tc.z;
    n.z = (((tc.z + tm.z) + tp.z) + tc.y) + tc.w;
    n.w = (((tc.w + tm.w) + tp.w) + tc.z) + tr;
    // n*0.2f*3.0f bit-identical to n/5.0f*3.0f for n in {0..5}
    a.x = n.x * 0.2f * 3.0f;
    a.y = n.y * 0.2f * 3.0f;
    a.z = n.z * 0.2f * 3.0f;
    a.w = n.w * 0.2f * 3.0f;
    return a;
}

__device__ __forceinline__ v4f p_row(v4f am, v4f ac, v4f ap, v4f tc,
                                     int lm1, int lp1) {
    float al = __shfl(ac.w, lm1);
    float ar = __shfl(ac.x, lp1);
    v4f p;
    {
        float d5 = (((ac.x + am.x) + ap.x) + al) + ac.y;
        float c5 = ((((ac.x - 1.0f) + (am.x - 1.0f)) + (ap.x - 1.0f)) + (al - 1.0f)) + (ac.y - 1.0f);
        p.x = (tc.x == 1.0f) ? c5 : d5;
    }
    {
        float d5 = (((ac.y + am.y) + ap.y) + ac.x) + ac.z;
        float c5 = ((((ac.y - 1.0f) + (am.y - 1.0f)) + (ap.y - 1.0f)) + (ac.x - 1.0f)) + (ac.z - 1.0f);
        p.y = (tc.y == 1.0f) ? c5 : d5;
    }
    {
        float d5 = (((ac.z + am.z) + ap.z) + ac.y) + ac.w;
        float c5 = ((((ac.z - 1.0f) + (am.z - 1.0f)) + (ap.z - 1.0f)) + (ac.y - 1.0f)) + (ac.w - 1.0f);
        p.z = (tc.z == 1.0f) ? c5 : d5;
    }
    {
        float d5 = (((ac.w + am.w) + ap.w) + ac.z) + ar;
        float c5 = ((((ac.w - 1.0f) + (am.w - 1.0f)) + (ap.w - 1.0f)) + (ac.z - 1.0f)) + (ar - 1.0f);
        p.w = (tc.w == 1.0f) ? c5 : d5;
    }
    return p;
}

__device__ __forceinline__ float fermi(float pc, float pnl, float pnr, float pnu, float pnd,
                                       float tc, float tnl, float tnr, float tnu, float tnd,
                                       float lpx, int k) {
    float pn = (k == 0) ? pnl : (k == 1) ? pnr : (k == 2) ? pnu : pnd;
    float tn = (k == 0) ? tnl : (k == 1) ? tnr : (k == 2) ? tnu : tnd;
    float d  = pc - pn;
    // fast path (rel err ~1e-5) with conservative uncertainty band
    float ef = __expf(d * 10.0f);
    float Wf = __builtin_amdgcn_rcpf(1.0f + ef);
    float eps = 1e-4f * Wf + 1e-37f;
    float res;
    if (lpx <= Wf - eps)      res = tn;
    else if (lpx > Wf + eps)  res = tc;
    else {
        // bit-exact reference path (verified absmax 0.0 in rounds 1-2-5-6)
        float arg = d / 0.1f;
        float e = (float)exp((double)arg);
        float W = 1.0f / (1.0f + e);
        res = (lpx <= W) ? tn : tc;
    }
    return res;
}

__global__ __launch_bounds__(256, 4) void spgg_fermi_kernel(
    const float* __restrict__ t,       // type matrix, 0.0/1.0
    const float* __restrict__ lp,      // learning probabilities
    const int*   __restrict__ dir,     // learning direction 0..3
    float* __restrict__ out)
{
    const int lane = threadIdx.x & 63;
    const int wv   = threadIdx.x >> 6;

    // bijective XCD swizzle: nwg = 2304 = 8 * 288
    const int orig = blockIdx.x;
    const int e    = (orig & 7) * 288 + (orig >> 3);
    const int s    = e >> 7;                   // strip 0..17
    const int bg   = e & 127;                  // 0..127
    const int band = bg * 4 + wv;              // 0..511
    const int r0   = band * BANDH;
    const int cb   = s * OUTW - 12;            // lane-0 col of this strip
    const int col  = (cb + 4 * lane) & LMASK;  // 16B-aligned, wrapped
    const int lm1  = (lane + 63) & 63;
    const int lp1  = (lane + 1) & 63;
    const bool valid = (lane >= 3) && (lane <= 60);

    auto ldT  = [&](int r_) -> v4f { return *(const v4f*)&t[((r_ & LMASK) << 12) + col]; };
    auto ldLP = [&](int r_) -> v4f {
        return __builtin_nontemporal_load((const v4f*)&lp[((r_ & LMASK) << 12) + col]);
    };
    auto ldDR = [&](int r_) -> v4i {
        return __builtin_nontemporal_load((const v4i*)&dir[((r_ & LMASK) << 12) + col]);
    };

    // ---- warmup: fill pipeline for output row r0 ----
    v4f u0 = ldT(r0 - 3), u1 = ldT(r0 - 2), u2 = ldT(r0 - 1), u3 = ldT(r0);
    v4f u4 = ldT(r0 + 1), u5 = ldT(r0 + 2), u6 = ldT(r0 + 3);
    v4f LPc = ldLP(r0);
    v4i DRc = ldDR(r0);

    float tlA, trA, tlB, trB, tlC, trC, tlD, trD, ts0, ts1;
    v4f aM2 = a_row(u0, u1, u2, lm1, lp1, ts0, ts1);     // a(r0-2)
    v4f aM1 = a_row(u1, u2, u3, lm1, lp1, ts0, ts1);     // a(r0-1)
    v4f A0  = a_row(u2, u3, u4, lm1, lp1, tlA, trA);     // a(r0),   t-edges row r0
    v4f A1  = a_row(u3, u4, u5, lm1, lp1, tlB, trB);     // a(r0+1), t-edges row r0+1
    v4f P0  = p_row(aM2, aM1, A0, u2, lm1, lp1);         // p(r0-1)
    v4f P1  = p_row(aM1, A0, A1, u3, lm1, lp1);          // p(r0)

    v4f T0 = u2, T1 = u3, T2 = u4, T3 = u5, T4 = u6;     // t(r-1 .. r+3)

    // ---- main loop: TWO output rows per iteration (6 loads in flight) ----
    #pragma unroll 2
    for (int ii = 0; ii < BANDH; ii += 2) {
        const int r = r0 + ii;

        v4f Tn4 = ldT(r + 4);
        v4f Tn5 = ldT(r + 5);
        v4f LP1 = ldLP(r + 1);
        v4f LP2 = ldLP(r + 2);
        v4i DR1 = ldDR(r + 1);
        v4i DR2 = ldDR(r + 2);

        v4f A2 = a_row(T2, T3, T4,  lm1, lp1, tlC, trC);  // a(r+2), t-edges row r+2
        v4f A3 = a_row(T3, T4, Tn4, lm1, lp1, tlD, trD);  // a(r+3), t-edges row r+3
        v4f P2 = p_row(A0, A1, A2, T2, lm1, lp1);         // p(r+1)
        v4f P3 = p_row(A1, A2, A3, T3, lm1, lp1);         // p(r+2)

        // ---- output row r ----
        {
            float plx = __shfl(P1.w, lm1);
            float prx = __shfl(P1.x, lp1);
            v4f o;
            o.x = fermi(P1.x, plx,  P1.y, P0.x, P2.x, T1.x, tlA,  T1.y, T0.x, T2.x, LPc.x, DRc.x);
            o.y = fermi(P1.y, P1.x, P1.z, P0.y, P2.y, T1.y, T1.x, T1.z, T0.y, T2.y, LPc.y, DRc.y);
            o.z = fermi(P1.z, P1.y, P1.w, P0.z, P2.z, T1.z, T1.y, T1.w, T0.z, T2.z, LPc.z, DRc.z);
            o.w = fermi(P1.w, P1.z, prx,  P0.w, P2.w, T1.w, T1.z, trA,  T0.w, T2.w, LPc.w, DRc.w);
            if (valid) *(v4f*)&out[(r << 12) + col] = o;     // cached store: L2 merges
        }

        // ---- output row r+1 ----
        {
            float plx = __shfl(P2.w, lm1);
            float prx = __shfl(P2.x, lp1);
            v4f o;
            o.x = fermi(P2.x, plx,  P2.y, P1.x, P3.x, T2.x, tlB,  T2.y, T1.x, T3.x, LP1.x, DR1.x);
            o.y = fermi(P2.y, P2.x, P2.z, P1.y, P3.y, T2.y, T2.x, T2.z, T1.y, T3.y, LP1.y, DR1.y);
            o.z = fermi(P2.z, P2.y, P2.w, P1.z, P3.z, T2.z, T2.y, T2.w, T1.z, T3.z, LP1.z, DR1.z);
            o.w = fermi(P2.w, P2.z, prx,  P1.w, P3.w, T2.w, T2.z, trB,  T1.w, T3.w, LP1.w, DR1.w);
            if (valid) *(v4f*)&out[((r + 1) << 12) + col] = o;
        }

        // ---- rotate pipeline state by 2 rows ----
        T0 = T2; T1 = T3; T2 = T4; T3 = Tn4; T4 = Tn5;
        A0 = A2; A1 = A3;
        P0 = P2; P1 = P3;
        tlA = tlC; trA = trC; tlB = tlD; trB = trD;
        LPc = LP2; DRc = DR2;
    }
}

extern "C" void kernel_launch(void* const* d_in, const int* in_sizes, int n_in,
                              void* d_out, int out_size, void* d_ws, size_t ws_size,
                              hipStream_t stream)
{
    const float* t   = (const float*)d_in[0];
    const float* lp  = (const float*)d_in[1];
    const int*   dir = (const int*)d_in[2];
    float* out = (float*)d_out;

    // 18 strips x 128 block-groups (4 waves/block = 4 bands of 8 rows)
    dim3 grid(STRIPS * 128);   // 2304 blocks
    dim3 block(256);
    hipLaunchKernelGGL(spgg_fermi_kernel, grid, block, 0, stream, t, lp, dir, out);
}

// Round 11
// 218.383 us; speedup vs baseline: 1.0904x; 1.0904x over previous
//
#include <hip/hip_runtime.h>
#include <math.h>

// SPGG Fermi update, L=4096 periodic lattice — lane-local v5.
// v4 -> v5 (correctness hardening after post-timing divergence in R10):
//   - REMOVED all __builtin_nontemporal_* hints (plain cached loads/stores).
//     R10: first launch exact, graph replays consistently diverged; NT loads
//     interacting with the harness's D2D pristine-restore are the suspect.
//   - __launch_bounds__(256,3) instead of (256,4): v4's ~140 live VGPRs would
//     spill under the 128-VGPR cap of (,4); avoid scratch under graph capture.
//   - T0 kept center-only (v4f) to cut live state.
// Structure unchanged from v4: lane-local 12-wide t loads (3 aligned float4),
// no cross-lane shuffles, 256-col strips tiling 4096 exactly (full 128B-line
// stores), bijective XCD swizzle. f32 op order identical per site to the
// verified absmax-0.0 kernels.

#define LSZ 4096
#define LMASK 4095
#define BANDH 8          // rows per wave

typedef float v4f __attribute__((ext_vector_type(4)));
typedef int   v4i __attribute__((ext_vector_type(4)));

struct R12 { v4f l, c, r; };          // t cols c-4..c-1, c..c+3, c+4..c+7
struct A8  { v4f lo, hi; };           // a cols c-2..c+1, c+2..c+5
struct P6  { v4f lo; float p3, p4; }; // p cols c-1..c+2, c+3, c+4

// n*0.2f*3.0f is bit-identical to n/5.0f*3.0f for all n in {0..5}
#define AMUL(n) (((n) * 0.2f) * 3.0f)

__device__ __forceinline__ A8 a_row(const R12& tm, const R12& tc, const R12& tp) {
    A8 a;
    // reference order: ((((center + up) + down) + left) + right)
    a.lo.x = AMUL((((tc.l.z + tm.l.z) + tp.l.z) + tc.l.y) + tc.l.w); // j=-2
    a.lo.y = AMUL((((tc.l.w + tm.l.w) + tp.l.w) + tc.l.z) + tc.c.x); // j=-1
    a.lo.z = AMUL((((tc.c.x + tm.c.x) + tp.c.x) + tc.l.w) + tc.c.y); // j= 0
    a.lo.w = AMUL((((tc.c.y + tm.c.y) + tp.c.y) + tc.c.x) + tc.c.z); // j= 1
    a.hi.x = AMUL((((tc.c.z + tm.c.z) + tp.c.z) + tc.c.y) + tc.c.w); // j= 2
    a.hi.y = AMUL((((tc.c.w + tm.c.w) + tp.c.w) + tc.c.z) + tc.r.x); // j= 3
    a.hi.z = AMUL((((tc.r.x + tm.r.x) + tp.r.x) + tc.c.w) + tc.r.y); // j= 4
    a.hi.w = AMUL((((tc.r.y + tm.r.y) + tp.r.y) + tc.r.x) + tc.r.z); // j= 5
    return a;
}

__device__ __forceinline__ float pcol(float aC, float aU, float aD,
                                      float aL, float aR, float tv) {
    float d5 = (((aC + aU) + aD) + aL) + aR;
    float c5 = ((((aC - 1.0f) + (aU - 1.0f)) + (aD - 1.0f))
                + (aL - 1.0f)) + (aR - 1.0f);
    return (tv == 1.0f) ? c5 : d5;
}

__device__ __forceinline__ P6 p_row(const A8& am, const A8& ac, const A8& ap,
                                    const R12& tc) {
    P6 p;
    p.lo.x = pcol(ac.lo.y, am.lo.y, ap.lo.y, ac.lo.x, ac.lo.z, tc.l.w); // j=-1
    p.lo.y = pcol(ac.lo.z, am.lo.z, ap.lo.z, ac.lo.y, ac.lo.w, tc.c.x); // j= 0
    p.lo.z = pcol(ac.lo.w, am.lo.w, ap.lo.w, ac.lo.z, ac.hi.x, tc.c.y); // j= 1
    p.lo.w = pcol(ac.hi.x, am.hi.x, ap.hi.x, ac.lo.w, ac.hi.y, tc.c.z); // j= 2
    p.p3   = pcol(ac.hi.y, am.hi.y, ap.hi.y, ac.hi.x, ac.hi.z, tc.c.w); // j= 3
    p.p4   = pcol(ac.hi.z, am.hi.z, ap.hi.z, ac.hi.y, ac.hi.w, tc.r.x); // j= 4
    return p;
}

__device__ __forceinline__ float fermi(float pc, float pnl, float pnr, float pnu, float pnd,
                                       float tc, float tnl, float tnr, float tnu, float tnd,
                                       float lpx, int k) {
    float pn = (k == 0) ? pnl : (k == 1) ? pnr : (k == 2) ? pnu : pnd;
    float tn = (k == 0) ? tnl : (k == 1) ? tnr : (k == 2) ? tnu : tnd;
    float d  = pc - pn;
    // fast path (rel err ~1e-5) with conservative uncertainty band
    float ef = __expf(d * 10.0f);
    float Wf = __builtin_amdgcn_rcpf(1.0f + ef);
    float eps = 1e-4f * Wf + 1e-37f;
    float res;
    if (lpx <= Wf - eps)      res = tn;
    else if (lpx > Wf + eps)  res = tc;
    else {
        // bit-exact reference path (verified absmax 0.0 in rounds 1-2-5-6-8)
        float arg = d / 0.1f;
        float e = (float)exp((double)arg);
        float W = 1.0f / (1.0f + e);
        res = (lpx <= W) ? tn : tc;
    }
    return res;
}

__global__ __launch_bounds__(256, 3) void spgg_fermi_kernel(
    const float* __restrict__ t,       // type matrix, 0.0/1.0
    const float* __restrict__ lp,      // learning probabilities
    const int*   __restrict__ dir,     // learning direction 0..3
    float* __restrict__ out)
{
    const int lane = threadIdx.x & 63;
    const int wv   = threadIdx.x >> 6;

    // bijective XCD swizzle: nwg = 2048 = 8 * 256; XCD x owns strips 2x, 2x+1
    const int orig = blockIdx.x;
    const int e    = (orig & 7) * 256 + (orig >> 3);
    const int s    = e >> 7;                   // strip 0..15
    const int bg   = e & 127;                  // 0..127
    const int band = bg * 4 + wv;              // 0..511
    const int r0   = band * BANDH;
    const int col  = s * 256 + 4 * lane;       // exact tiling, 16B aligned
    const int colL = (col - 4) & LMASK;
    const int colR = (col + 4) & LMASK;

    auto ldR = [&](int r_) -> R12 {
        const int base = (r_ & LMASK) << 12;
        R12 x;
        x.l = *(const v4f*)&t[base + colL];
        x.c = *(const v4f*)&t[base + col];
        x.r = *(const v4f*)&t[base + colR];
        return x;
    };
    auto ldLP = [&](int r_) -> v4f {
        return *(const v4f*)&lp[((r_ & LMASK) << 12) + col];
    };
    auto ldDR = [&](int r_) -> v4i {
        return *(const v4i*)&dir[((r_ & LMASK) << 12) + col];
    };

    // ---- warmup: fill pipeline for output row r0 ----
    R12 u3 = ldR(r0 - 3), u2 = ldR(r0 - 2), u1 = ldR(r0 - 1);
    R12 T1 = ldR(r0), T2 = ldR(r0 + 1), T3 = ldR(r0 + 2), T4 = ldR(r0 + 3);
    v4f LPc = ldLP(r0);
    v4i DRc = ldDR(r0);

    A8 aM2 = a_row(u3, u2, u1);     // a(r0-2)
    A8 aM1 = a_row(u2, u1, T1);     // a(r0-1)
    A8 A0  = a_row(u1, T1, T2);     // a(r0)
    A8 A1  = a_row(T1, T2, T3);     // a(r0+1)
    P6 P0  = p_row(aM2, aM1, A0, u1);   // p(r0-1)
    P6 P1  = p_row(aM1, A0, A1, T1);    // p(r0)

    v4f T0c = u1.c;                 // t(r0-1), center 4 cols (up-neighbor t)

    // ---- main loop: one output row per iteration ----
    #pragma unroll 2
    for (int i = 0; i < BANDH; ++i) {
        const int r = r0 + i;

        // t(r+4) is consumed only NEXT iteration (a(r+3)) -> depth-2 pipeline
        R12 T5  = ldR(r + 4);
        v4f LPn = ldLP(r + 1);
        v4i DRn = ldDR(r + 1);

        A8 A2 = a_row(T2, T3, T4);          // a(r+2)
        P6 P2 = p_row(A0, A1, A2, T2);      // p(r+1)

        v4f o;
        o.x = fermi(P1.lo.y, P1.lo.x, P1.lo.z, P0.lo.y, P2.lo.y,
                    T1.c.x, T1.l.w, T1.c.y, T0c.x, T2.c.x, LPc.x, DRc.x);
        o.y = fermi(P1.lo.z, P1.lo.y, P1.lo.w, P0.lo.z, P2.lo.z,
                    T1.c.y, T1.c.x, T1.c.z, T0c.y, T2.c.y, LPc.y, DRc.y);
        o.z = fermi(P1.lo.w, P1.lo.z, P1.p3, P0.lo.w, P2.lo.w,
                    T1.c.z, T1.c.y, T1.c.w, T0c.z, T2.c.z, LPc.z, DRc.z);
        o.w = fermi(P1.p3, P1.lo.w, P1.p4, P0.p3, P2.p3,
                    T1.c.w, T1.c.z, T1.r.x, T0c.w, T2.c.w, LPc.w, DRc.w);

        *(v4f*)&out[(r << 12) + col] = o;   // full 128B lines, no partials

        // rotate pipeline state
        T0c = T1.c;
        T1 = T2; T2 = T3; T3 = T4; T4 = T5;
        A0 = A1; A1 = A2;
        P0 = P1; P1 = P2;
        LPc = LPn; DRc = DRn;
    }
}

extern "C" void kernel_launch(void* const* d_in, const int* in_sizes, int n_in,
                              void* d_out, int out_size, void* d_ws, size_t ws_size,
                              hipStream_t stream)
{
    const float* t   = (const float*)d_in[0];
    const float* lp  = (const float*)d_in[1];
    const int*   dir = (const int*)d_in[2];
    float* out = (float*)d_out;

    // 16 strips x 128 block-groups (4 waves/block = 4 bands of 8 rows)
    dim3 grid(16 * 128);   // 2048 blocks
    dim3 block(256);
    hipLaunchKernelGGL(spgg_fermi_kernel, grid, block, 0, stream, t, lp, dir, out);
}